// Round 4
// baseline (259.512 us; speedup 1.0000x reference)
//
#include <hip/hip_runtime.h>
#include <math.h>

#define T_STEPS 256
#define BS      512
#define N       2048
#define BLOCK   64                // ONE wave per batch element: no barriers in the scan
#define EPT     (N / BLOCK)       // 32 elements per thread
#define NP      (EPT / 2)         // 16 packed float2 per thread
#define NQ      (EPT / 4)         // 8 float4 chunks per thread
#define FUDGE   1e-4f

typedef float v2f __attribute__((ext_vector_type(2)));
typedef float v4f __attribute__((ext_vector_type(4)));

static __device__ __forceinline__ v2f lo2(v4f a) { return __builtin_shufflevector(a, a, 0, 1); }
static __device__ __forceinline__ v2f hi2(v4f a) { return __builtin_shufflevector(a, a, 2, 3); }

// --- packed fp32 math (VOP3P, gfx90a+/gfx950). One instr = 2 lanes of fma. ---
// NB: packed-f32 set is only {fma,mul,add,mov} -- no v_pk_max_f32; relu stays scalar.
__device__ __forceinline__ v2f pk_fma(v2f a, v2f b, v2f c) {
    v2f d;
    asm("v_pk_fma_f32 %0, %1, %2, %3" : "=v"(d) : "v"(a), "v"(b), "v"(c));
    return d;
}
__device__ __forceinline__ v2f pk_add(v2f a, v2f b) {
    v2f d;
    asm("v_pk_add_f32 %0, %1, %2" : "=v"(d) : "v"(a), "v"(b));
    return d;
}

// --- wave64 sum via DPP: lane 63 holds the wave total --------------------
template <int CTRL>
__device__ __forceinline__ float dpp_add(float v) {
    int sh = __builtin_amdgcn_update_dpp(0, __float_as_int(v), CTRL, 0xf, 0xf, true);
    return v + __int_as_float(sh);
}

__device__ __forceinline__ float wave_sum_lane63(float v) {
    v = dpp_add<0x111>(v);  // row_shr:1
    v = dpp_add<0x112>(v);  // row_shr:2
    v = dpp_add<0x114>(v);  // row_shr:4
    v = dpp_add<0x118>(v);  // row_shr:8
    v = dpp_add<0x142>(v);  // row_bcast:15
    v = dpp_add<0x143>(v);  // row_bcast:31
    return v;               // total valid in lane 63
}

__device__ __forceinline__ float bcast63(float v) {
    return __int_as_float(__builtin_amdgcn_readlane(__float_as_int(v), 63));
}

// R12: three rounds of source-level hints failed to make the 96 coefficient
// VGPRs resident (VGPR_Count stuck at 132; per-step global reloads with
// ~200cy L2 latency exposed = the ~950cy/step stall). New plan: stage
// cb/cw/cq in LDS (24 KB). ds_read_b128 addresses are step-invariant (no
// dependence on x), latency ~120cy and throughput ~12cy -- schedulable
// under the serial head. Robust both ways: with the 512-VGPR budget LICM
// may hoist the invariant LDS reads into registers (the ideal); if RA
// refuses, in-loop ds_reads replace global reloads at ~2x lower cost.
__global__ __launch_bounds__(BLOCK) __attribute__((amdgpu_waves_per_eu(1, 1)))
void legacy_elbo_scan_kernel(
    const float* __restrict__ noises,   // [T, BS]
    const float* __restrict__ ys,       // [T]
    const float* __restrict__ qs,       // [T]
    const float* __restrict__ z_biases, // [N]
    const float* __restrict__ w_in,     // [N]
    const float* __restrict__ w_inq,    // [N]
    const float* __restrict__ p_llr,
    const float* __restrict__ p_llrd,
    const float* __restrict__ p_sigb,
    const float* __restrict__ p_oscale,
    const float* __restrict__ p_ufs,
    const float* __restrict__ p_lwd,
    const float* __restrict__ p_qscale,
    const float* __restrict__ p_tauq,
    const float* __restrict__ p_tauy,
    float* __restrict__ out)            // [T, BS]
{
    const int tid = threadIdx.x;        // == lane
    const int blk = blockIdx.x;         // batch index k

    __shared__ float ys_s[T_STEPS];
    __shared__ float qs_s[T_STEPS];
    __shared__ float nz_s[T_STEPS];
    __shared__ v4f cb_s[N / 4];         // 8 KB: sigb * z_biases
    __shared__ v4f cw_s[N / 4];         // 8 KB: w_in
    __shared__ v4f cq_s[N / 4];         // 8 KB: w_inq

    for (int i = tid; i < T_STEPS; i += BLOCK) {
        ys_s[i] = ys[i];
        qs_s[i] = qs[i];
        nz_s[i] = noises[i * BS + blk];
    }

    const float sigb    = p_sigb[0];
    const float llr     = p_llr[0];
    const float llrd    = p_llrd[0];
    const float oscale  = p_oscale[0];
    const float ufs     = p_ufs[0];
    const float lwd     = p_lwd[0];
    const float qscale  = p_qscale[0];
    const float tauq_m1 = p_tauq[0];
    const float tauy_m1 = p_tauy[0];

    const float lr0      = expf(llr);
    const float lr_decay = expf(llrd);
    const float wd       = expf(lwd);
    const float rwd      = 1.0f / wd;
    const float tauq     = 1.0f + log1pf(expf(tauq_m1));
    const float tauy     = 1.0f + log1pf(expf(tauy_m1));
    const float omtq     = 1.0f - tauq;
    const float omty     = 1.0f - tauy;

    // One-time coalesced global -> LDS staging of the coefficient arrays.
    {
        const v4f* zb4 = (const v4f*)z_biases;
        const v4f* wi4 = (const v4f*)w_in;
        const v4f* wq4 = (const v4f*)w_inq;
#pragma unroll
        for (int c = 0; c < NQ; ++c) {
            const int idx = tid + c * BLOCK;     // 0..511 covers full arrays
            v4f b = zb4[idx];
            b *= sigb;
            cb_s[idx] = b;
            cw_s[idx] = wi4[idx];
            cq_s[idx] = wq4[idx];
        }
    }

    // Persistent per-thread state: 32 output weights in v-space (16 pairs).
    v2f v[NP];
#pragma unroll
    for (int i = 0; i < NP; ++i) v[i] = (v2f){0.0f, 0.0f};

    float u = 0.0f, e = 0.0f, lr_mult = 1.0f, qlp = 0.0f, ylp = 0.0f;
    float sp = 1.0f, rsp = 1.0f;        // wd^t and 1/wd^t

    __syncthreads();                    // single-wave block: nearly free, once

    float q_c = qs_s[0], y_c = ys_s[0], n_c = nz_s[0];

    for (int t = 0; t < T_STEPS; ++t) {
        const int tn = (t + 1 < T_STEPS) ? t + 1 : t;
        const float q_n = qs_s[tn], y_n = ys_s[tn], n_n = nz_s[tn];

        qlp = omtq * qlp + tauq * q_c;
        const float qsc = qscale * qlp;
        const float x   = fmaf(u, ufs, e) + n_c;
        const v2f xx = (v2f){x, x};
        const v2f qq = (v2f){qsc, qsc};

        v2f h[NP];
        v2f su_a[4], sh_a[4];
#pragma unroll
        for (int a = 0; a < 4; ++a) {
            su_a[a] = (v2f){0.0f, 0.0f};
            sh_a[a] = (v2f){0.0f, 0.0f};
        }
#pragma unroll
        for (int c = 0; c < NQ; ++c) {   // fully unrolled: all indices static
            const int idx = tid + c * BLOCK;
            const v4f b4 = cb_s[idx];    // ds_read_b128, step-invariant addr
            const v4f w4 = cw_s[idx];
            const v4f g4 = cq_s[idx];
            v2f t0 = pk_fma(qq, lo2(g4), lo2(b4));
            t0 = pk_fma(xx, lo2(w4), t0);
            v2f t1 = pk_fma(qq, hi2(g4), hi2(b4));
            t1 = pk_fma(xx, hi2(w4), t1);
            v2f h0, h1;
            h0.x = fmaxf(t0.x, 0.0f);
            h0.y = fmaxf(t0.y, 0.0f);
            h1.x = fmaxf(t1.x, 0.0f);
            h1.y = fmaxf(t1.y, 0.0f);
            h[2 * c]     = h0;
            h[2 * c + 1] = h1;
            su_a[0] = pk_fma(v[2 * c],     h0, su_a[0]);
            su_a[1] = pk_fma(v[2 * c + 1], h1, su_a[1]);
            sh_a[2] = pk_fma(h0, h0, sh_a[2]);
            sh_a[3] = pk_fma(h1, h1, sh_a[3]);
        }
        v2f su2 = pk_add(su_a[0], su_a[1]);
        v2f sh2 = pk_add(sh_a[2], sh_a[3]);
        float su_l = su2.x + su2.y;
        float sh_l = sh2.x + sh2.y;

        // Wave-only reduction: DPP to lane 63, then readlane -> SGPR broadcast.
        const float su_w = wave_sum_lane63(su_l);
        const float sh_w = wave_sum_lane63(sh_l);
        const float su_t = bcast63(su_w);
        const float sh_t = bcast63(sh_w);

        u = sp * su_t;                   // w_t = sp * v_t
        if (tid == 0) out[t * BS + blk] = oscale * u;

        ylp = omty * ylp + tauy * y_c;
        e = ylp - u;
        const float el = e * (lr0 * lr_mult);
        const float c  = el * rsp;       // dw coefficient in v-space
        const v2f cc = (v2f){c, c};

#pragma unroll
        for (int i = 0; i < NP; ++i)
            v[i] = pk_fma(cc, h[i], v[i]);

        const float nrm = sqrtf(fmaf(el * el, sh_t, FUDGE));
        lr_mult *= __expf(-lr_decay * nrm);
        sp  *= wd;
        rsp *= rwd;

        q_c = q_n; y_c = y_n; n_c = n_n;
    }
}

extern "C" void kernel_launch(void* const* d_in, const int* in_sizes, int n_in,
                              void* d_out, int out_size, void* d_ws, size_t ws_size,
                              hipStream_t stream) {
    (void)in_sizes; (void)n_in; (void)d_ws; (void)ws_size; (void)out_size;
    const float* noises   = (const float*)d_in[0];
    const float* ys       = (const float*)d_in[1];
    const float* qs       = (const float*)d_in[2];
    const float* z_biases = (const float*)d_in[3];
    const float* w_in     = (const float*)d_in[4];
    const float* w_inq    = (const float*)d_in[5];
    const float* llr      = (const float*)d_in[6];
    const float* llrd     = (const float*)d_in[7];
    const float* sigb     = (const float*)d_in[8];
    const float* oscale   = (const float*)d_in[9];
    const float* ufs      = (const float*)d_in[10];
    const float* lwd      = (const float*)d_in[11];
    const float* qscale   = (const float*)d_in[12];
    const float* tauq     = (const float*)d_in[13];
    const float* tauy     = (const float*)d_in[14];
    float* out = (float*)d_out;

    hipLaunchKernelGGL(legacy_elbo_scan_kernel, dim3(BS), dim3(BLOCK), 0, stream,
                       noises, ys, qs, z_biases, w_in, w_inq,
                       llr, llrd, sigb, oscale, ufs, lwd, qscale, tauq, tauy,
                       out);
}

// Round 5
// 242.888 us; speedup vs baseline: 1.0684x; 1.0684x over previous
//
#include <hip/hip_runtime.h>
#include <math.h>

#define T_STEPS 256
#define BS      512
#define N       2048
#define BLOCK   128               // 2 waves per batch element
#define NWAVE   (BLOCK / 64)      // 2
#define EPT     (N / BLOCK)       // 16 elements per thread
#define NQ      (EPT / 4)         // 4 float4 chunks per thread
#define FUDGE   1e-4f

// --- wave64 sum via DPP: lane 63 holds the wave total --------------------
template <int CTRL>
__device__ __forceinline__ float dpp_add(float v) {
    int sh = __builtin_amdgcn_update_dpp(0, __float_as_int(v), CTRL, 0xf, 0xf, true);
    return v + __int_as_float(sh);
}

__device__ __forceinline__ float wave_sum_lane63(float v) {
    v = dpp_add<0x111>(v);  // row_shr:1
    v = dpp_add<0x112>(v);  // row_shr:2
    v = dpp_add<0x114>(v);  // row_shr:4
    v = dpp_add<0x118>(v);  // row_shr:8
    v = dpp_add<0x142>(v);  // row_bcast:15
    v = dpp_add<0x143>(v);  // row_bcast:31
    return v;               // total valid in lane 63
}

// R13: rounds 9-12 established the wall is coefficient REFETCH BANDWIDTH:
// the RA refused to keep 96 coeff VGPRs resident at EPT=32 (pins spill to
// scratch = same L2 traffic; LDS staging = worse, JIT ds_read latency).
// Quantitative: 24.5KB/wave/step from L2 = ~93us floor (matches R9's 154).
// Fix: make residency CHEAP instead of forced. 2 waves per batch element,
// EPT=16 -> 48 coeff floats/lane, total ~110 VGPRs, comfortably under the
// two-arg __launch_bounds__(128,2) 256-reg cap -- the configuration family
// (R8: (256,2)) where coefficients PROVABLY stayed resident. Costs one
// 2-wave LDS exchange per step (single-barrier parity trick, R8-proven).
// All SIMDs now active (1024 waves = 4/CU). No inline asm this round.
__global__ __launch_bounds__(BLOCK, 2)
void legacy_elbo_scan_kernel(
    const float* __restrict__ noises,   // [T, BS]
    const float* __restrict__ ys,       // [T]
    const float* __restrict__ qs,       // [T]
    const float* __restrict__ z_biases, // [N]
    const float* __restrict__ w_in,     // [N]
    const float* __restrict__ w_inq,    // [N]
    const float* __restrict__ p_llr,
    const float* __restrict__ p_llrd,
    const float* __restrict__ p_sigb,
    const float* __restrict__ p_oscale,
    const float* __restrict__ p_ufs,
    const float* __restrict__ p_lwd,
    const float* __restrict__ p_qscale,
    const float* __restrict__ p_tauq,
    const float* __restrict__ p_tauy,
    float* __restrict__ out)            // [T, BS]
{
    const int tid  = threadIdx.x;
    const int wid  = tid >> 6;          // 0..1
    const int lane = tid & 63;
    const int blk  = blockIdx.x;        // batch index k

    __shared__ float ys_s[T_STEPS];
    __shared__ float qs_s[T_STEPS];
    __shared__ float nz_s[T_STEPS];
    __shared__ __align__(16) float red[2][4];   // [parity][wave*2 + {su,sh2}]

    for (int i = tid; i < T_STEPS; i += BLOCK) {
        ys_s[i] = ys[i];
        qs_s[i] = qs[i];
        nz_s[i] = noises[i * BS + blk];
    }

    const float sigb    = p_sigb[0];
    const float llr     = p_llr[0];
    const float llrd    = p_llrd[0];
    const float oscale  = p_oscale[0];
    const float ufs     = p_ufs[0];
    const float lwd     = p_lwd[0];
    const float qscale  = p_qscale[0];
    const float tauq_m1 = p_tauq[0];
    const float tauy_m1 = p_tauy[0];

    const float lr0      = expf(llr);
    const float lr_decay = expf(llrd);
    const float wd       = expf(lwd);
    const float rwd      = 1.0f / wd;
    const float tauq     = 1.0f + log1pf(expf(tauq_m1));
    const float tauy     = 1.0f + log1pf(expf(tauy_m1));
    const float omtq     = 1.0f - tauq;
    const float omty     = 1.0f - tauy;

    // Coefficients resident in registers: 3 arrays x 4 float4 = 48 VGPRs.
    const float4* zb4 = (const float4*)z_biases;
    const float4* wi4 = (const float4*)w_in;
    const float4* wq4 = (const float4*)w_inq;
    float4 cb_r[NQ], cw_r[NQ], cq_r[NQ];
#pragma unroll
    for (int c = 0; c < NQ; ++c) {
        const int idx = tid + c * BLOCK;     // 0..511, coalesced 16B/lane
        float4 b = zb4[idx];
        b.x *= sigb; b.y *= sigb; b.z *= sigb; b.w *= sigb;
        cb_r[c] = b;
        cw_r[c] = wi4[idx];
        cq_r[c] = wq4[idx];
    }

    // Persistent per-thread state: 16 output weights in v-space.
    float v[EPT];
#pragma unroll
    for (int i = 0; i < EPT; ++i) v[i] = 0.0f;

    float u = 0.0f, e = 0.0f, lr_mult = 1.0f, qlp = 0.0f, ylp = 0.0f;
    float sp = 1.0f, rsp = 1.0f;        // wd^t and 1/wd^t

    __syncthreads();

    float q_c = qs_s[0], y_c = ys_s[0], n_c = nz_s[0];

    for (int t = 0; t < T_STEPS; ++t) {
        const int tn = (t + 1 < T_STEPS) ? t + 1 : t;
        const float q_n = qs_s[tn], y_n = ys_s[tn], n_n = nz_s[tn];

        qlp = omtq * qlp + tauq * q_c;
        const float qsc = qscale * qlp;
        const float x   = fmaf(u, ufs, e) + n_c;

        float su0 = 0.f, su1 = 0.f, sh0 = 0.f, sh1 = 0.f;
        float h[EPT];
#pragma unroll
        for (int c = 0; c < NQ; ++c) {
            const float4 b4 = cb_r[c];
            const float4 w4 = cw_r[c];
            const float4 g4 = cq_r[c];
            float h0 = fmaxf(fmaf(x, w4.x, fmaf(qsc, g4.x, b4.x)), 0.0f);
            float h1 = fmaxf(fmaf(x, w4.y, fmaf(qsc, g4.y, b4.y)), 0.0f);
            float h2 = fmaxf(fmaf(x, w4.z, fmaf(qsc, g4.z, b4.z)), 0.0f);
            float h3 = fmaxf(fmaf(x, w4.w, fmaf(qsc, g4.w, b4.w)), 0.0f);
            h[4*c+0] = h0; h[4*c+1] = h1; h[4*c+2] = h2; h[4*c+3] = h3;
            su0 = fmaf(v[4*c+0], h0, su0);
            su1 = fmaf(v[4*c+1], h1, su1);
            su0 = fmaf(v[4*c+2], h2, su0);
            su1 = fmaf(v[4*c+3], h3, su1);
            sh0 = fmaf(h0, h0, sh0);
            sh1 = fmaf(h1, h1, sh1);
            sh0 = fmaf(h2, h2, sh0);
            sh1 = fmaf(h3, h3, sh1);
        }
        const float su_w = wave_sum_lane63(su0 + su1);
        const float sh_w = wave_sum_lane63(sh0 + sh1);

        const int p = t & 1;
        if (lane == 63) {
            red[p][wid * 2]     = su_w;
            red[p][wid * 2 + 1] = sh_w;
        }
        __syncthreads();                // single barrier per step (parity-safe)
        const float4 r = *(const float4*)&red[p][0];
        const float su_t = r.x + r.z;
        const float sh2  = r.y + r.w;

        u = sp * su_t;                  // w_t = sp * v_t
        if (tid == 0) out[t * BS + blk] = oscale * u;

        ylp = omty * ylp + tauy * y_c;
        e = ylp - u;
        const float el = e * (lr0 * lr_mult);
        const float c  = el * rsp;      // dw coefficient in v-space

#pragma unroll
        for (int i = 0; i < EPT; ++i)
            v[i] = fmaf(c, h[i], v[i]);

        const float nrm = sqrtf(fmaf(el * el, sh2, FUDGE));
        lr_mult *= __expf(-lr_decay * nrm);
        sp  *= wd;
        rsp *= rwd;

        q_c = q_n; y_c = y_n; n_c = n_n;
    }
}

extern "C" void kernel_launch(void* const* d_in, const int* in_sizes, int n_in,
                              void* d_out, int out_size, void* d_ws, size_t ws_size,
                              hipStream_t stream) {
    (void)in_sizes; (void)n_in; (void)d_ws; (void)ws_size; (void)out_size;
    const float* noises   = (const float*)d_in[0];
    const float* ys       = (const float*)d_in[1];
    const float* qs       = (const float*)d_in[2];
    const float* z_biases = (const float*)d_in[3];
    const float* w_in     = (const float*)d_in[4];
    const float* w_inq    = (const float*)d_in[5];
    const float* llr      = (const float*)d_in[6];
    const float* llrd     = (const float*)d_in[7];
    const float* sigb     = (const float*)d_in[8];
    const float* oscale   = (const float*)d_in[9];
    const float* ufs      = (const float*)d_in[10];
    const float* lwd      = (const float*)d_in[11];
    const float* qscale   = (const float*)d_in[12];
    const float* tauq     = (const float*)d_in[13];
    const float* tauy     = (const float*)d_in[14];
    float* out = (float*)d_out;

    hipLaunchKernelGGL(legacy_elbo_scan_kernel, dim3(BS), dim3(BLOCK), 0, stream,
                       noises, ys, qs, z_biases, w_in, w_inq,
                       llr, llrd, sigb, oscale, ufs, lwd, qscale, tauq, tauy,
                       out);
}

// Round 6
// 199.388 us; speedup vs baseline: 1.3015x; 1.2182x over previous
//
#include <hip/hip_runtime.h>
#include <math.h>
#include <stdint.h>

#define T_STEPS 256
#define BS      512
#define N       2048
#define BLOCK   64
#define FUDGE   1e-4f

// R14: whole-scan inline asm. Rounds 9-13 proved the AMDGPU RA will not keep
// the 96 coefficient values resident no matter what (VGPR_Count 56-132 across
// 5 variants; per-step refetch/refill from L2-backed memory ~49KB/CU/step is
// the 1360-1780 cy/step wall). Inside one asm block there is no RA: the
// coefficients live in v32-v127 by construction, w_out state in v128-v159,
// h in v160-v191. Per-step memory traffic: 3 scalar s_loads (prefetched one
// step ahead) + one lane-0 store. Packed v_pk_fma_f32 for the element math.
__global__ __launch_bounds__(BLOCK) __attribute__((amdgpu_waves_per_eu(1, 1)))
void legacy_elbo_scan_kernel(
    const float* __restrict__ noises,   // [T, BS]
    const float* __restrict__ ys,       // [T]
    const float* __restrict__ qs,       // [T]
    const float* __restrict__ z_biases, // [N]
    const float* __restrict__ w_in,     // [N]
    const float* __restrict__ w_inq,    // [N]
    const float* __restrict__ p_llr,
    const float* __restrict__ p_llrd,
    const float* __restrict__ p_sigb,
    const float* __restrict__ p_oscale,
    const float* __restrict__ p_ufs,
    const float* __restrict__ p_lwd,
    const float* __restrict__ p_qscale,
    const float* __restrict__ p_tauq,
    const float* __restrict__ p_tauy,
    float* __restrict__ out)            // [T, BS]
{
    const int tid = threadIdx.x;
    const int blk = blockIdx.x;

    const float sigb    = p_sigb[0];
    const float lr0     = expf(p_llr[0]);
    const float lr_decay= expf(p_llrd[0]);
    const float wd      = expf(p_lwd[0]);
    const float rwd     = 1.0f / wd;
    const float tauq    = 1.0f + log1pf(expf(p_tauq[0]));
    const float tauy    = 1.0f + log1pf(expf(p_tauy[0]));
    const float omtq    = 1.0f - tauq;
    const float omty    = 1.0f - tauy;
    const float qscale  = p_qscale[0];
    const float ufs     = p_ufs[0];
    const float oscale  = p_oscale[0];
    // __expf(x) == exp2(x * log2(e)); fold -lr_decay into the multiplier.
    const float nld2    = -lr_decay * 1.4426950408889634f;

    const float* nzp = noises + blk;    // uniform: per-block noise column base
    const int    ovo = blk * 4;         // byte offset of out[0*BS+blk]

    asm volatile(
        // ---------------- prologue: coefficient loads -> v32..v127 ----------
        "v_lshlrev_b32 v7, 4, %[vtid]\n\t"          // tid*16 bytes
        "v_add_u32 v5, 0x1000, v7\n\t"              // +4096 for chunks 4..7
        "global_load_dwordx4 v[32:35],  v7, %[pzb]\n\t"
        "global_load_dwordx4 v[36:39],  v7, %[pzb] offset:1024\n\t"
        "global_load_dwordx4 v[40:43],  v7, %[pzb] offset:2048\n\t"
        "global_load_dwordx4 v[44:47],  v7, %[pzb] offset:3072\n\t"
        "global_load_dwordx4 v[48:51],  v5, %[pzb]\n\t"
        "global_load_dwordx4 v[52:55],  v5, %[pzb] offset:1024\n\t"
        "global_load_dwordx4 v[56:59],  v5, %[pzb] offset:2048\n\t"
        "global_load_dwordx4 v[60:63],  v5, %[pzb] offset:3072\n\t"
        "global_load_dwordx4 v[64:67],  v7, %[pwi]\n\t"
        "global_load_dwordx4 v[68:71],  v7, %[pwi] offset:1024\n\t"
        "global_load_dwordx4 v[72:75],  v7, %[pwi] offset:2048\n\t"
        "global_load_dwordx4 v[76:79],  v7, %[pwi] offset:3072\n\t"
        "global_load_dwordx4 v[80:83],  v5, %[pwi]\n\t"
        "global_load_dwordx4 v[84:87],  v5, %[pwi] offset:1024\n\t"
        "global_load_dwordx4 v[88:91],  v5, %[pwi] offset:2048\n\t"
        "global_load_dwordx4 v[92:95],  v5, %[pwi] offset:3072\n\t"
        "global_load_dwordx4 v[96:99],  v7, %[pwq]\n\t"
        "global_load_dwordx4 v[100:103], v7, %[pwq] offset:1024\n\t"
        "global_load_dwordx4 v[104:107], v7, %[pwq] offset:2048\n\t"
        "global_load_dwordx4 v[108:111], v7, %[pwq] offset:3072\n\t"
        "global_load_dwordx4 v[112:115], v5, %[pwq]\n\t"
        "global_load_dwordx4 v[116:119], v5, %[pwq] offset:1024\n\t"
        "global_load_dwordx4 v[120:123], v5, %[pwq] offset:2048\n\t"
        "global_load_dwordx4 v[124:127], v5, %[pwq] offset:3072\n\t"
        "s_waitcnt vmcnt(0)\n\t"
        // scale biases by sigma_b
        "v_mul_f32 v32, %[osg], v32\n\t"  "v_mul_f32 v33, %[osg], v33\n\t"
        "v_mul_f32 v34, %[osg], v34\n\t"  "v_mul_f32 v35, %[osg], v35\n\t"
        "v_mul_f32 v36, %[osg], v36\n\t"  "v_mul_f32 v37, %[osg], v37\n\t"
        "v_mul_f32 v38, %[osg], v38\n\t"  "v_mul_f32 v39, %[osg], v39\n\t"
        "v_mul_f32 v40, %[osg], v40\n\t"  "v_mul_f32 v41, %[osg], v41\n\t"
        "v_mul_f32 v42, %[osg], v42\n\t"  "v_mul_f32 v43, %[osg], v43\n\t"
        "v_mul_f32 v44, %[osg], v44\n\t"  "v_mul_f32 v45, %[osg], v45\n\t"
        "v_mul_f32 v46, %[osg], v46\n\t"  "v_mul_f32 v47, %[osg], v47\n\t"
        "v_mul_f32 v48, %[osg], v48\n\t"  "v_mul_f32 v49, %[osg], v49\n\t"
        "v_mul_f32 v50, %[osg], v50\n\t"  "v_mul_f32 v51, %[osg], v51\n\t"
        "v_mul_f32 v52, %[osg], v52\n\t"  "v_mul_f32 v53, %[osg], v53\n\t"
        "v_mul_f32 v54, %[osg], v54\n\t"  "v_mul_f32 v55, %[osg], v55\n\t"
        "v_mul_f32 v56, %[osg], v56\n\t"  "v_mul_f32 v57, %[osg], v57\n\t"
        "v_mul_f32 v58, %[osg], v58\n\t"  "v_mul_f32 v59, %[osg], v59\n\t"
        "v_mul_f32 v60, %[osg], v60\n\t"  "v_mul_f32 v61, %[osg], v61\n\t"
        "v_mul_f32 v62, %[osg], v62\n\t"  "v_mul_f32 v63, %[osg], v63\n\t"
        // zero w_out state v128..v159
        "v_mov_b32 v128, 0\n\t" "v_mov_b32 v129, 0\n\t" "v_mov_b32 v130, 0\n\t" "v_mov_b32 v131, 0\n\t"
        "v_mov_b32 v132, 0\n\t" "v_mov_b32 v133, 0\n\t" "v_mov_b32 v134, 0\n\t" "v_mov_b32 v135, 0\n\t"
        "v_mov_b32 v136, 0\n\t" "v_mov_b32 v137, 0\n\t" "v_mov_b32 v138, 0\n\t" "v_mov_b32 v139, 0\n\t"
        "v_mov_b32 v140, 0\n\t" "v_mov_b32 v141, 0\n\t" "v_mov_b32 v142, 0\n\t" "v_mov_b32 v143, 0\n\t"
        "v_mov_b32 v144, 0\n\t" "v_mov_b32 v145, 0\n\t" "v_mov_b32 v146, 0\n\t" "v_mov_b32 v147, 0\n\t"
        "v_mov_b32 v148, 0\n\t" "v_mov_b32 v149, 0\n\t" "v_mov_b32 v150, 0\n\t" "v_mov_b32 v151, 0\n\t"
        "v_mov_b32 v152, 0\n\t" "v_mov_b32 v153, 0\n\t" "v_mov_b32 v154, 0\n\t" "v_mov_b32 v155, 0\n\t"
        "v_mov_b32 v156, 0\n\t" "v_mov_b32 v157, 0\n\t" "v_mov_b32 v158, 0\n\t" "v_mov_b32 v159, 0\n\t"
        // state: qlp v20, ylp v21, u v22, e v23, lr_mult v24, sp v25, rsp v26
        "v_mov_b32 v20, 0\n\t" "v_mov_b32 v21, 0\n\t" "v_mov_b32 v22, 0\n\t" "v_mov_b32 v23, 0\n\t"
        "v_mov_b32 v24, 1.0\n\t" "v_mov_b32 v25, 1.0\n\t" "v_mov_b32 v26, 1.0\n\t"
        "v_mov_b32 v6, %[ovo]\n\t"                  // out byte-offset
        "s_mov_b32 s60, 0\n\t"                      // t
        "s_mov_b32 s61, 0\n\t"                      // y/q byte offset (t*4)
        "s_mov_b32 s62, 0\n\t"                      // nz byte offset (t*2048)
        "s_load_dword s66, %[pys], s61\n\t"
        "s_load_dword s67, %[pqs], s61\n\t"
        "s_load_dword s68, %[pnz], s62\n\t"
        "s_waitcnt lgkmcnt(0)\n\t"
        // ---------------- main scan loop ------------------------------------
        "Lelbo0:\n\t"
        // prefetch next step's scalars (clamped at T-1)
        "s_add_u32 s63, s61, 4\n\t"
        "s_min_u32 s63, s63, 0x3fc\n\t"
        "s_add_u32 s64, s62, 0x800\n\t"
        "s_min_u32 s64, s64, 0x7f800\n\t"
        "s_load_dword s69, %[pys], s63\n\t"
        "s_load_dword s70, %[pqs], s63\n\t"
        "s_load_dword s71, %[pnz], s64\n\t"
        // qlp = omtq*qlp + tauq*q ; qsc pair in v[10:11]
        "v_mov_b32 v30, s67\n\t"
        "v_mul_f32 v20, %[omq], v20\n\t"
        "v_fmac_f32 v20, %[otq], v30\n\t"
        "v_mul_f32 v10, %[oq], v20\n\t"
        "v_mov_b32 v11, v10\n\t"
        // x = e + nz + ufs*u ; pair in v[8:9]
        "v_mov_b32 v8, s68\n\t"
        "v_add_f32 v8, v23, v8\n\t"
        "v_fmac_f32 v8, %[ouf], v22\n\t"
        "v_mov_b32 v9, v8\n\t"
        // zero accumulators: su v[12:13]+v[14:15], sh v[16:17]+v[18:19]
        "v_mov_b32 v12, 0\n\t" "v_mov_b32 v13, 0\n\t" "v_mov_b32 v14, 0\n\t" "v_mov_b32 v15, 0\n\t"
        "v_mov_b32 v16, 0\n\t" "v_mov_b32 v17, 0\n\t" "v_mov_b32 v18, 0\n\t" "v_mov_b32 v19, 0\n\t"
        // h = relu(cb + x*cw + qsc*cq)  (16 packed pairs)
        "v_pk_fma_f32 v[160:161], v[10:11], v[96:97],  v[32:33]\n\t"
        "v_pk_fma_f32 v[162:163], v[10:11], v[98:99],  v[34:35]\n\t"
        "v_pk_fma_f32 v[164:165], v[10:11], v[100:101], v[36:37]\n\t"
        "v_pk_fma_f32 v[166:167], v[10:11], v[102:103], v[38:39]\n\t"
        "v_pk_fma_f32 v[168:169], v[10:11], v[104:105], v[40:41]\n\t"
        "v_pk_fma_f32 v[170:171], v[10:11], v[106:107], v[42:43]\n\t"
        "v_pk_fma_f32 v[172:173], v[10:11], v[108:109], v[44:45]\n\t"
        "v_pk_fma_f32 v[174:175], v[10:11], v[110:111], v[46:47]\n\t"
        "v_pk_fma_f32 v[176:177], v[10:11], v[112:113], v[48:49]\n\t"
        "v_pk_fma_f32 v[178:179], v[10:11], v[114:115], v[50:51]\n\t"
        "v_pk_fma_f32 v[180:181], v[10:11], v[116:117], v[52:53]\n\t"
        "v_pk_fma_f32 v[182:183], v[10:11], v[118:119], v[54:55]\n\t"
        "v_pk_fma_f32 v[184:185], v[10:11], v[120:121], v[56:57]\n\t"
        "v_pk_fma_f32 v[186:187], v[10:11], v[122:123], v[58:59]\n\t"
        "v_pk_fma_f32 v[188:189], v[10:11], v[124:125], v[60:61]\n\t"
        "v_pk_fma_f32 v[190:191], v[10:11], v[126:127], v[62:63]\n\t"
        "v_pk_fma_f32 v[160:161], v[8:9], v[64:65], v[160:161]\n\t"
        "v_pk_fma_f32 v[162:163], v[8:9], v[66:67], v[162:163]\n\t"
        "v_pk_fma_f32 v[164:165], v[8:9], v[68:69], v[164:165]\n\t"
        "v_pk_fma_f32 v[166:167], v[8:9], v[70:71], v[166:167]\n\t"
        "v_pk_fma_f32 v[168:169], v[8:9], v[72:73], v[168:169]\n\t"
        "v_pk_fma_f32 v[170:171], v[8:9], v[74:75], v[170:171]\n\t"
        "v_pk_fma_f32 v[172:173], v[8:9], v[76:77], v[172:173]\n\t"
        "v_pk_fma_f32 v[174:175], v[8:9], v[78:79], v[174:175]\n\t"
        "v_pk_fma_f32 v[176:177], v[8:9], v[80:81], v[176:177]\n\t"
        "v_pk_fma_f32 v[178:179], v[8:9], v[82:83], v[178:179]\n\t"
        "v_pk_fma_f32 v[180:181], v[8:9], v[84:85], v[180:181]\n\t"
        "v_pk_fma_f32 v[182:183], v[8:9], v[86:87], v[182:183]\n\t"
        "v_pk_fma_f32 v[184:185], v[8:9], v[88:89], v[184:185]\n\t"
        "v_pk_fma_f32 v[186:187], v[8:9], v[90:91], v[186:187]\n\t"
        "v_pk_fma_f32 v[188:189], v[8:9], v[92:93], v[188:189]\n\t"
        "v_pk_fma_f32 v[190:191], v[8:9], v[94:95], v[190:191]\n\t"
        "v_max_f32 v160, 0, v160\n\t" "v_max_f32 v161, 0, v161\n\t"
        "v_max_f32 v162, 0, v162\n\t" "v_max_f32 v163, 0, v163\n\t"
        "v_max_f32 v164, 0, v164\n\t" "v_max_f32 v165, 0, v165\n\t"
        "v_max_f32 v166, 0, v166\n\t" "v_max_f32 v167, 0, v167\n\t"
        "v_max_f32 v168, 0, v168\n\t" "v_max_f32 v169, 0, v169\n\t"
        "v_max_f32 v170, 0, v170\n\t" "v_max_f32 v171, 0, v171\n\t"
        "v_max_f32 v172, 0, v172\n\t" "v_max_f32 v173, 0, v173\n\t"
        "v_max_f32 v174, 0, v174\n\t" "v_max_f32 v175, 0, v175\n\t"
        "v_max_f32 v176, 0, v176\n\t" "v_max_f32 v177, 0, v177\n\t"
        "v_max_f32 v178, 0, v178\n\t" "v_max_f32 v179, 0, v179\n\t"
        "v_max_f32 v180, 0, v180\n\t" "v_max_f32 v181, 0, v181\n\t"
        "v_max_f32 v182, 0, v182\n\t" "v_max_f32 v183, 0, v183\n\t"
        "v_max_f32 v184, 0, v184\n\t" "v_max_f32 v185, 0, v185\n\t"
        "v_max_f32 v186, 0, v186\n\t" "v_max_f32 v187, 0, v187\n\t"
        "v_max_f32 v188, 0, v188\n\t" "v_max_f32 v189, 0, v189\n\t"
        "v_max_f32 v190, 0, v190\n\t" "v_max_f32 v191, 0, v191\n\t"
        // su += v.h ; sh += h.h (2 packed accumulators each)
        "v_pk_fma_f32 v[12:13], v[128:129], v[160:161], v[12:13]\n\t"
        "v_pk_fma_f32 v[16:17], v[160:161], v[160:161], v[16:17]\n\t"
        "v_pk_fma_f32 v[14:15], v[130:131], v[162:163], v[14:15]\n\t"
        "v_pk_fma_f32 v[18:19], v[162:163], v[162:163], v[18:19]\n\t"
        "v_pk_fma_f32 v[12:13], v[132:133], v[164:165], v[12:13]\n\t"
        "v_pk_fma_f32 v[16:17], v[164:165], v[164:165], v[16:17]\n\t"
        "v_pk_fma_f32 v[14:15], v[134:135], v[166:167], v[14:15]\n\t"
        "v_pk_fma_f32 v[18:19], v[166:167], v[166:167], v[18:19]\n\t"
        "v_pk_fma_f32 v[12:13], v[136:137], v[168:169], v[12:13]\n\t"
        "v_pk_fma_f32 v[16:17], v[168:169], v[168:169], v[16:17]\n\t"
        "v_pk_fma_f32 v[14:15], v[138:139], v[170:171], v[14:15]\n\t"
        "v_pk_fma_f32 v[18:19], v[170:171], v[170:171], v[18:19]\n\t"
        "v_pk_fma_f32 v[12:13], v[140:141], v[172:173], v[12:13]\n\t"
        "v_pk_fma_f32 v[16:17], v[172:173], v[172:173], v[16:17]\n\t"
        "v_pk_fma_f32 v[14:15], v[142:143], v[174:175], v[14:15]\n\t"
        "v_pk_fma_f32 v[18:19], v[174:175], v[174:175], v[18:19]\n\t"
        "v_pk_fma_f32 v[12:13], v[144:145], v[176:177], v[12:13]\n\t"
        "v_pk_fma_f32 v[16:17], v[176:177], v[176:177], v[16:17]\n\t"
        "v_pk_fma_f32 v[14:15], v[146:147], v[178:179], v[14:15]\n\t"
        "v_pk_fma_f32 v[18:19], v[178:179], v[178:179], v[18:19]\n\t"
        "v_pk_fma_f32 v[12:13], v[148:149], v[180:181], v[12:13]\n\t"
        "v_pk_fma_f32 v[16:17], v[180:181], v[180:181], v[16:17]\n\t"
        "v_pk_fma_f32 v[14:15], v[150:151], v[182:183], v[14:15]\n\t"
        "v_pk_fma_f32 v[18:19], v[182:183], v[182:183], v[18:19]\n\t"
        "v_pk_fma_f32 v[12:13], v[152:153], v[184:185], v[12:13]\n\t"
        "v_pk_fma_f32 v[16:17], v[184:185], v[184:185], v[16:17]\n\t"
        "v_pk_fma_f32 v[14:15], v[154:155], v[186:187], v[14:15]\n\t"
        "v_pk_fma_f32 v[18:19], v[186:187], v[186:187], v[18:19]\n\t"
        "v_pk_fma_f32 v[12:13], v[156:157], v[188:189], v[12:13]\n\t"
        "v_pk_fma_f32 v[16:17], v[188:189], v[188:189], v[16:17]\n\t"
        "v_pk_fma_f32 v[14:15], v[158:159], v[190:191], v[14:15]\n\t"
        "v_pk_fma_f32 v[18:19], v[190:191], v[190:191], v[18:19]\n\t"
        // horizontal combine -> su in v12, sh in v16
        "v_add_f32 v12, v12, v14\n\t"
        "v_add_f32 v13, v13, v15\n\t"
        "v_add_f32 v16, v16, v18\n\t"
        "v_add_f32 v17, v17, v19\n\t"
        "v_add_f32 v12, v12, v13\n\t"
        "v_add_f32 v16, v16, v17\n\t"
        // wave reduce to lane 63 (DPP), su chain v12/tmp v30, sh chain v16/tmp v31
        "s_nop 1\n\t"
        "v_mov_b32_dpp v30, v12 row_shr:1 row_mask:0xf bank_mask:0xf\n\t"
        "v_mov_b32_dpp v31, v16 row_shr:1 row_mask:0xf bank_mask:0xf\n\t"
        "v_add_f32 v12, v12, v30\n\t"
        "v_add_f32 v16, v16, v31\n\t"
        "s_nop 0\n\t"
        "v_mov_b32_dpp v30, v12 row_shr:2 row_mask:0xf bank_mask:0xf\n\t"
        "v_mov_b32_dpp v31, v16 row_shr:2 row_mask:0xf bank_mask:0xf\n\t"
        "v_add_f32 v12, v12, v30\n\t"
        "v_add_f32 v16, v16, v31\n\t"
        "s_nop 0\n\t"
        "v_mov_b32_dpp v30, v12 row_shr:4 row_mask:0xf bank_mask:0xf\n\t"
        "v_mov_b32_dpp v31, v16 row_shr:4 row_mask:0xf bank_mask:0xf\n\t"
        "v_add_f32 v12, v12, v30\n\t"
        "v_add_f32 v16, v16, v31\n\t"
        "s_nop 0\n\t"
        "v_mov_b32_dpp v30, v12 row_shr:8 row_mask:0xf bank_mask:0xf\n\t"
        "v_mov_b32_dpp v31, v16 row_shr:8 row_mask:0xf bank_mask:0xf\n\t"
        "v_add_f32 v12, v12, v30\n\t"
        "v_add_f32 v16, v16, v31\n\t"
        "s_nop 0\n\t"
        "v_mov_b32_dpp v30, v12 row_bcast:15 row_mask:0xf bank_mask:0xf\n\t"
        "v_mov_b32_dpp v31, v16 row_bcast:15 row_mask:0xf bank_mask:0xf\n\t"
        "v_add_f32 v12, v12, v30\n\t"
        "v_add_f32 v16, v16, v31\n\t"
        "s_nop 0\n\t"
        "v_mov_b32_dpp v30, v12 row_bcast:31 row_mask:0xf bank_mask:0xf\n\t"
        "v_mov_b32_dpp v31, v16 row_bcast:31 row_mask:0xf bank_mask:0xf\n\t"
        "v_add_f32 v12, v12, v30\n\t"
        "v_add_f32 v16, v16, v31\n\t"
        "s_nop 1\n\t"
        "v_readlane_b32 s74, v12, 63\n\t"           // su_t
        "v_readlane_b32 s75, v16, 63\n\t"           // sh_t
        // u = sp * su_t ; store oscale*u from lane 0
        "v_mul_f32 v22, s74, v25\n\t"
        "v_mul_f32 v30, %[oos], v22\n\t"
        "s_mov_b64 s[72:73], exec\n\t"
        "s_mov_b64 exec, 1\n\t"
        "global_store_dword v6, v30, %[pou]\n\t"
        "s_mov_b64 exec, s[72:73]\n\t"
        "v_add_u32 v6, 0x800, v6\n\t"               // next row (+BS*4 bytes)
        // ylp, e, el, c
        "v_mov_b32 v30, s66\n\t"
        "v_mul_f32 v21, %[omy], v21\n\t"
        "v_fmac_f32 v21, %[oty], v30\n\t"
        "v_sub_f32 v23, v21, v22\n\t"               // e = ylp - u
        "v_mul_f32 v27, %[olr], v23\n\t"
        "v_mul_f32 v27, v27, v24\n\t"               // el = e*lr0*lr_mult
        "v_mul_f32 v28, v27, v26\n\t"               // c = el*rsp
        "v_mov_b32 v29, v28\n\t"
        // v += c*h (16 packed)
        "v_pk_fma_f32 v[128:129], v[28:29], v[160:161], v[128:129]\n\t"
        "v_pk_fma_f32 v[130:131], v[28:29], v[162:163], v[130:131]\n\t"
        "v_pk_fma_f32 v[132:133], v[28:29], v[164:165], v[132:133]\n\t"
        "v_pk_fma_f32 v[134:135], v[28:29], v[166:167], v[134:135]\n\t"
        "v_pk_fma_f32 v[136:137], v[28:29], v[168:169], v[136:137]\n\t"
        "v_pk_fma_f32 v[138:139], v[28:29], v[170:171], v[138:139]\n\t"
        "v_pk_fma_f32 v[140:141], v[28:29], v[172:173], v[140:141]\n\t"
        "v_pk_fma_f32 v[142:143], v[28:29], v[174:175], v[142:143]\n\t"
        "v_pk_fma_f32 v[144:145], v[28:29], v[176:177], v[144:145]\n\t"
        "v_pk_fma_f32 v[146:147], v[28:29], v[178:179], v[146:147]\n\t"
        "v_pk_fma_f32 v[148:149], v[28:29], v[180:181], v[148:149]\n\t"
        "v_pk_fma_f32 v[150:151], v[28:29], v[182:183], v[150:151]\n\t"
        "v_pk_fma_f32 v[152:153], v[28:29], v[184:185], v[152:153]\n\t"
        "v_pk_fma_f32 v[154:155], v[28:29], v[186:187], v[154:155]\n\t"
        "v_pk_fma_f32 v[156:157], v[28:29], v[188:189], v[156:157]\n\t"
        "v_pk_fma_f32 v[158:159], v[28:29], v[190:191], v[158:159]\n\t"
        // lr_mult *= exp2(nld2 * sqrt(el^2*sh_t + FUDGE)) ; sp,rsp update
        "v_mul_f32 v30, v27, v27\n\t"
        "v_mul_f32 v30, s75, v30\n\t"
        "v_add_f32 v30, 0x38d1b717, v30\n\t"        // + 1e-4f
        "v_sqrt_f32 v30, v30\n\t"
        "s_nop 1\n\t"
        "v_mul_f32 v30, %[ond], v30\n\t"
        "v_exp_f32 v30, v30\n\t"
        "s_nop 1\n\t"
        "v_mul_f32 v24, v24, v30\n\t"
        "v_mul_f32 v25, %[owd], v25\n\t"
        "v_mul_f32 v26, %[orw], v26\n\t"
        // commit prefetched scalars, advance, loop
        "s_waitcnt lgkmcnt(0)\n\t"
        "s_mov_b32 s66, s69\n\t"
        "s_mov_b32 s67, s70\n\t"
        "s_mov_b32 s68, s71\n\t"
        "s_mov_b32 s61, s63\n\t"
        "s_mov_b32 s62, s64\n\t"
        "s_add_u32 s60, s60, 1\n\t"
        "s_cmp_lt_u32 s60, 0x100\n\t"
        "s_cbranch_scc1 Lelbo0\n\t"
        "s_waitcnt vmcnt(0)\n\t"                    // drain stores before endpgm
        :
        : [pys]"s"(ys), [pqs]"s"(qs), [pnz]"s"(nzp), [pou]"s"(out),
          [pzb]"s"(z_biases), [pwi]"s"(w_in), [pwq]"s"(w_inq),
          [vtid]"v"(tid), [ovo]"v"(ovo),
          [osg]"v"(sigb), [otq]"v"(tauq), [omq]"v"(omtq),
          [oty]"v"(tauy), [omy]"v"(omty), [oq]"v"(qscale),
          [ouf]"v"(ufs), [olr]"v"(lr0), [owd]"v"(wd), [orw]"v"(rwd),
          [oos]"v"(oscale), [ond]"v"(nld2)
        : "memory", "scc",
          "s60","s61","s62","s63","s64","s65","s66","s67","s68","s69",
          "s70","s71","s72","s73","s74","s75",
          "v2","v3","v4","v5","v6","v7","v8","v9","v10","v11",
          "v12","v13","v14","v15","v16","v17","v18","v19","v20","v21",
          "v22","v23","v24","v25","v26","v27","v28","v29","v30","v31",
          "v32","v33","v34","v35","v36","v37","v38","v39","v40","v41",
          "v42","v43","v44","v45","v46","v47","v48","v49","v50","v51",
          "v52","v53","v54","v55","v56","v57","v58","v59","v60","v61",
          "v62","v63","v64","v65","v66","v67","v68","v69","v70","v71",
          "v72","v73","v74","v75","v76","v77","v78","v79","v80","v81",
          "v82","v83","v84","v85","v86","v87","v88","v89","v90","v91",
          "v92","v93","v94","v95","v96","v97","v98","v99","v100","v101",
          "v102","v103","v104","v105","v106","v107","v108","v109","v110","v111",
          "v112","v113","v114","v115","v116","v117","v118","v119","v120","v121",
          "v122","v123","v124","v125","v126","v127","v128","v129","v130","v131",
          "v132","v133","v134","v135","v136","v137","v138","v139","v140","v141",
          "v142","v143","v144","v145","v146","v147","v148","v149","v150","v151",
          "v152","v153","v154","v155","v156","v157","v158","v159","v160","v161",
          "v162","v163","v164","v165","v166","v167","v168","v169","v170","v171",
          "v172","v173","v174","v175","v176","v177","v178","v179","v180","v181",
          "v182","v183","v184","v185","v186","v187","v188","v189","v190","v191"
    );
}

extern "C" void kernel_launch(void* const* d_in, const int* in_sizes, int n_in,
                              void* d_out, int out_size, void* d_ws, size_t ws_size,
                              hipStream_t stream) {
    (void)in_sizes; (void)n_in; (void)d_ws; (void)ws_size; (void)out_size;
    const float* noises   = (const float*)d_in[0];
    const float* ys       = (const float*)d_in[1];
    const float* qs       = (const float*)d_in[2];
    const float* z_biases = (const float*)d_in[3];
    const float* w_in     = (const float*)d_in[4];
    const float* w_inq    = (const float*)d_in[5];
    const float* llr      = (const float*)d_in[6];
    const float* llrd     = (const float*)d_in[7];
    const float* sigb     = (const float*)d_in[8];
    const float* oscale   = (const float*)d_in[9];
    const float* ufs      = (const float*)d_in[10];
    const float* lwd      = (const float*)d_in[11];
    const float* qscale   = (const float*)d_in[12];
    const float* tauq     = (const float*)d_in[13];
    const float* tauy     = (const float*)d_in[14];
    float* out = (float*)d_out;

    hipLaunchKernelGGL(legacy_elbo_scan_kernel, dim3(BS), dim3(BLOCK), 0, stream,
                       noises, ys, qs, z_biases, w_in, w_inq,
                       llr, llrd, sigb, oscale, ufs, lwd, qscale, tauq, tauy,
                       out);
}